// Round 9
// baseline (180.550 us; speedup 1.0000x reference)
//
#include <hip/hip_runtime.h>
#include <hip/hip_bf16.h>

// out[b,i,k] = sum_j tanh(bn2( relu(bn1( [x_i,x_j,adj_ij] @ W1 )) @ W2 ))[k]
// Phase-1: acc = P1[h] + adj@W1a (MFMA K=16 pad 32); epilogue += P2 (f32 global/L2), relu -> h1b
// Phase-2: h1b @ W2 frags loaded per s-step from L2 (blinded ptr, no persistent regs)
// LDS: h1b 32K + adjbf 4K = 36K -> 4 blocks/CU at <=64 VGPR.

typedef short short8 __attribute__((ext_vector_type(8)));
typedef float f32x4 __attribute__((ext_vector_type(4)));

#define EPSV 1e-5f
#define TWO_LOG2E 2.885390081777927f

// ws float offsets
#define OFF_P1T  0         // [1024][256] f32
#define OFF_P2S  262144    // [1024][256] f32 row-major ([b*512+j][h])
#define OFF_S1   524288
#define OFF_T1   524544
#define OFF_T2   524800    // t2 * 2log2e
#define OFF_W1F  525056    // bf16 frags [16][64][8] = 8192 shorts = 4096 floats
#define OFF_W2F  529152    // bf16 frags [128][64][8] = 65536 shorts = 32768 floats

__device__ __forceinline__ short f2bf(float f) {
    unsigned u = __builtin_bit_cast(unsigned, f);
    u += 0x7fffu + ((u >> 16) & 1u);
    return (short)(u >> 16);
}

__device__ __forceinline__ unsigned pk2bf(float lo, float hi) {
    unsigned u;
    asm("v_cvt_pk_bf16_f32 %0, %1, %2" : "=v"(u) : "v"(lo), "v"(hi));
    return u;
}

__global__ void prep_scalars(const float* __restrict__ g1, const float* __restrict__ b1,
                             const float* __restrict__ m1, const float* __restrict__ v1,
                             const float* __restrict__ g2, const float* __restrict__ b2,
                             const float* __restrict__ m2, const float* __restrict__ v2,
                             float* __restrict__ wsf) {
    int t = threadIdx.x;  // h (0..255)
    float s1 = g1[t] * __frsqrt_rn(v1[t] + EPSV);
    float t1 = b1[t] - m1[t] * s1;
    float s2 = g2[t] * __frsqrt_rn(v2[t] + EPSV);
    float t2 = b2[t] - m2[t] * s2;
    wsf[OFF_S1 + t] = s1;
    wsf[OFF_T1 + t] = t1;
    wsf[OFF_T2 + t] = t2 * TWO_LOG2E;
}

// W1a fragments [16][64][8]: frag f = w*2+n, lane l: col=(f>>1)*32+(f&1)*16+(l&15),
// k = (l>>4)*8+e (k<16 real, else 0), val = W1[(256+k)*256+col]*s1[col]
__global__ void prep_w1f(const float* __restrict__ W1, float* __restrict__ wsf) {
    int tid = blockIdx.x * 256 + threadIdx.x;  // 0..1023
    int f = tid >> 6, l = tid & 63;
    int col = (f >> 1) * 32 + (f & 1) * 16 + (l & 15);
    int kb = (l >> 4) * 8;
    float s1 = wsf[OFF_S1 + col];
    short8 v;
#pragma unroll
    for (int e = 0; e < 8; ++e) {
        int k = kb + e;
        v[e] = (k < 16) ? f2bf(W1[(256 + k) * 256 + col] * s1) : (short)0;
    }
    *(short8*)((short*)(wsf + OFF_W1F) + tid * 8) = v;
}

// W2 fragments [128][64][8]: frag f = w*16+n*8+s, lane l: col = w*32+n*16+(l&15),
// k = s*32+(l>>4)*8+e, val = W2[k*256+col]*s2[col]*2log2e
__global__ void prep_w2f(const float* __restrict__ W2,
                         const float* __restrict__ g2, const float* __restrict__ v2,
                         float* __restrict__ wsf) {
    int tid = blockIdx.x * 256 + threadIdx.x;  // 0..8191
    int f = tid >> 6, l = tid & 63;
    int w = f >> 4, n = (f >> 3) & 1, s = f & 7;
    int col = w * 32 + n * 16 + (l & 15);
    int kb = s * 32 + (l >> 4) * 8;
    float s2 = g2[col] * __frsqrt_rn(v2[col] + EPSV) * TWO_LOG2E;
    short8 v;
#pragma unroll
    for (int e = 0; e < 8; ++e)
        v[e] = f2bf(W2[(kb + e) * 256 + col] * s2);
    *(short8*)((short*)(wsf + OFF_W2F) + tid * 8) = v;
}

// P1t f32 + P2S f32 row-major
__global__ void prep_p(const float* __restrict__ inp, const float* __restrict__ W1,
                       float* __restrict__ wsf) {
    int bn = blockIdx.x, h = threadIdx.x;
    const float* x = inp + (size_t)bn * 128;
    float a1 = 0.f, a2 = 0.f;
    for (int c = 0; c < 128; ++c) {
        float xv = x[c];
        a1 = fmaf(xv, W1[c * 256 + h], a1);
        a2 = fmaf(xv, W1[(128 + c) * 256 + h], a2);
    }
    float s1 = wsf[OFF_S1 + h], t1 = wsf[OFF_T1 + h];
    wsf[OFF_P1T + (size_t)bn * 256 + h] = a1 * s1 + t1;
    wsf[OFF_P2S + (size_t)bn * 256 + h] = a2 * s1;
}

__global__ __launch_bounds__(512, 4) void propmain(
    const float* __restrict__ adj, const float* __restrict__ wsf,
    float* __restrict__ out) {
    __shared__ __align__(16) short h1b[64 * 256];   // bf16 H1, &15-swizzled (32 KB)
    __shared__ __align__(16) short adjbf[64 * 32];  // bf16 adj tile, chunk-XOR (4 KB)

    const int bi = blockIdx.x;
    const int b = bi >> 9;
    const int t = threadIdx.x;
    const int w = t >> 6, l = t & 63, r = l & 15, q = l >> 4;

    const float* P1t = wsf + OFF_P1T;
    const float* P2s = wsf + OFF_P2S + (size_t)b * 512 * 256;
    const float* t2p = wsf + OFF_T2;
    const short* W1f = (const short*)(wsf + OFF_W1F);
    const short* W2f = (const short*)(wsf + OFF_W2F);
    const float* adjbase = adj + (size_t)bi * 512 * 16;

    float t2v[2], p1v[2];
#pragma unroll
    for (int n = 0; n < 2; ++n) {
        const int hc = w * 32 + n * 16 + r;
        t2v[n] = t2p[hc];
        p1v[n] = P1t[(size_t)bi * 256 + hc];
    }

    // adj staging constants
    const int arow_st = t >> 3, ks_st = (t & 7) * 2;
    const int aslot = arow_st * 32 + (((ks_st >> 3) ^ (arow_st & 3)) << 3) + (ks_st & 7);

    unsigned stadj;
#define LOAD_ADJ(JT) do {                                                       \
        const float2 _av = *(const float2*)(adjbase + (JT) * 1024 + t * 2);     \
        stadj = pk2bf(_av.x, _av.y);                                            \
    } while (0)

    // prologue: zero adjbf pads, stage adj tile 0
    if (t < 256) {
        short8 z = {0, 0, 0, 0, 0, 0, 0, 0};
        *(short8*)(adjbf + t * 8) = z;
    }
    LOAD_ADJ(0);
    __syncthreads();   // zeros visible before adj data writes
    *(unsigned*)(adjbf + aslot) = stadj;

    float part[2] = {0.f, 0.f};

    for (int jt = 0; jt < 8; ++jt) {
        __syncthreads();  // (A) adjbf(jt) visible; h1b free for rewrite

        if (jt < 7) LOAD_ADJ(jt + 1);  // global->reg, hides under phase 1

        // per-tile P2 base: rows jbase.., this lane's columns
        const float* p2t = P2s + (size_t)(jt * 64 + q * 4) * 256 + w * 32 + r;

        // ---- phase 1: acc = P1 + adj@W1a (MFMA); epilogue += P2 (f32), relu -> h1b ----
        const short* w1fw = W1f + (w * 2) * 512 + l * 8;
        const short8 bB1_0 = *(const short8*)(w1fw);
        const short8 bB1_1 = *(const short8*)(w1fw + 512);
#pragma unroll
        for (int rf = 0; rf < 4; ++rf) {
            const int arow = rf * 16 + r;
            const short8 aA1 = *(const short8*)(adjbf + arow * 32 + (q ^ (r & 3)) * 8);
            f32x4 a0 = {p1v[0], p1v[0], p1v[0], p1v[0]};
            f32x4 a1 = {p1v[1], p1v[1], p1v[1], p1v[1]};
            a0 = __builtin_amdgcn_mfma_f32_16x16x32_bf16(aA1, bB1_0, a0, 0, 0, 0);
            a1 = __builtin_amdgcn_mfma_f32_16x16x32_bf16(aA1, bB1_1, a1, 0, 0, 0);
            const float* p2rf = p2t + rf * 16 * 256;
#pragma unroll
            for (int n = 0; n < 2; ++n) {
                const f32x4 av = n ? a1 : a0;
                const int colb = w * 32 + n * 16 + r;
#pragma unroll
                for (int e = 0; e < 4; ++e) {
                    const int row2 = rf * 16 + q * 4 + e;
                    const float y = fmaxf(av[e] + p2rf[e * 256 + n * 16], 0.f);
                    h1b[(row2 << 8) + (colb ^ ((row2 & 15) << 3))] = f2bf(y);
                }
            }
        }
        __syncthreads();  // (B) h1b visible

        if (jt < 7) *(unsigned*)(adjbf + aslot) = stadj;  // adj tile jt+1

        // ---- phase 2: h1b @ W2 (frags loaded per s-step, blinded base) ----
        {
            const short* W2p = W2f + w * 8192 + l * 8;
            asm volatile("" : "+v"(W2p));  // opaque per tile: no hoist across jt
            f32x4 acc[4][2];
#pragma unroll
            for (int rf = 0; rf < 4; ++rf)
#pragma unroll
                for (int n = 0; n < 2; ++n)
                    acc[rf][n] = (f32x4){t2v[n], t2v[n], t2v[n], t2v[n]};
#pragma unroll
            for (int s = 0; s < 8; ++s) {
                const short8 f0 = *(const short8*)(W2p + s * 512);
                const short8 f1 = *(const short8*)(W2p + (8 + s) * 512);
#pragma unroll
                for (int rf = 0; rf < 4; ++rf) {
                    const int row = rf * 16 + r;
                    const short8 aA = *(const short8*)(
                        h1b + (row << 8) + ((s * 32 + q * 8) ^ ((row & 15) << 3)));
                    acc[rf][0] = __builtin_amdgcn_mfma_f32_16x16x32_bf16(
                        aA, f0, acc[rf][0], 0, 0, 0);
                    acc[rf][1] = __builtin_amdgcn_mfma_f32_16x16x32_bf16(
                        aA, f1, acc[rf][1], 0, 0, 0);
                }
            }
#pragma unroll
            for (int n = 0; n < 2; ++n) {
                float ps = 0.f;
#pragma unroll
                for (int rf = 0; rf < 4; ++rf)
#pragma unroll
                    for (int e = 0; e < 4; ++e) {
                        const float ex = exp2f(acc[rf][n][e]);
                        ps += __builtin_amdgcn_rcpf(ex + 1.f);
                    }
                part[n] += ps;
            }
        }
    }

    // sum_j tanh = 512 - 2*sum(rcp); reduce over q
#pragma unroll
    for (int n = 0; n < 2; ++n) {
        float v = part[n];
        v += __shfl_xor(v, 16, 64);
        v += __shfl_xor(v, 32, 64);
        if (q == 0) out[(size_t)bi * 256 + w * 32 + n * 16 + r] = 512.f - 2.f * v;
    }
#undef LOAD_ADJ
}

extern "C" void kernel_launch(void* const* d_in, const int* in_sizes, int n_in,
                              void* d_out, int out_size, void* d_ws, size_t ws_size,
                              hipStream_t stream) {
    (void)in_sizes; (void)n_in; (void)out_size; (void)ws_size;
    const float* inputs = (const float*)d_in[0];
    const float* adj    = (const float*)d_in[1];
    const float* W1     = (const float*)d_in[2];
    const float* g1     = (const float*)d_in[3];
    const float* b1     = (const float*)d_in[4];
    const float* m1     = (const float*)d_in[5];
    const float* v1     = (const float*)d_in[6];
    const float* W2     = (const float*)d_in[7];
    const float* g2     = (const float*)d_in[8];
    const float* b2     = (const float*)d_in[9];
    const float* m2     = (const float*)d_in[10];
    const float* v2     = (const float*)d_in[11];
    float* out = (float*)d_out;
    float* wsf = (float*)d_ws;

    prep_scalars<<<1, 256, 0, stream>>>(g1, b1, m1, v1, g2, b2, m2, v2, wsf);
    prep_w1f<<<4, 256, 0, stream>>>(W1, wsf);
    prep_w2f<<<32, 256, 0, stream>>>(W2, g2, v2, wsf);
    prep_p<<<1024, 256, 0, stream>>>(inputs, W1, wsf);
    propmain<<<1024, 512, 0, stream>>>(adj, wsf, out);
}

// Round 11
// 180.149 us; speedup vs baseline: 1.0022x; 1.0022x over previous
//
#include <hip/hip_runtime.h>
#include <hip/hip_bf16.h>

// out[b,i,k] = sum_j tanh(bn2( relu(bn1( [x_i,x_j,adj_ij] @ W1 )) @ W2 ))[k]
// j-tile = 32. Phase-1: acc = P1[h] + adj@W1a (MFMA K=16 pad 32);
//   epilogue += P2 (bf16 reg-prefetched from transposed L2 image), relu -> h1b.
// Phase-2: h1b @ W2 frags loaded per s-step from L2 (blinded ptr).
// LDS 18 KB (h1b 16K + adj 2K) -> 3-4 blocks/CU.

typedef short sh4 __attribute__((ext_vector_type(4)));
typedef short short8 __attribute__((ext_vector_type(8)));
typedef float f32x4 __attribute__((ext_vector_type(4)));

#define EPSV 1e-5f
#define TWO_LOG2E 2.885390081777927f

// ws float offsets
#define OFF_P1T  0         // [1024][256] f32
#define OFF_P2T  262144    // bf16 image [2][256 h][512 j] = 131072 floats
#define OFF_S1   393216
#define OFF_T1   393472
#define OFF_T2   393728    // t2 * 2log2e
#define OFF_W1F  393984    // bf16 frags [16][64][8] = 4096 floats
#define OFF_W2F  398080    // bf16 frags [128][64][8] = 32768 floats

__device__ __forceinline__ short f2bf(float f) {
    unsigned u = __builtin_bit_cast(unsigned, f);
    u += 0x7fffu + ((u >> 16) & 1u);
    return (short)(u >> 16);
}

__device__ __forceinline__ float bf2f(short s) {
    unsigned u = ((unsigned)(unsigned short)s) << 16;
    return __builtin_bit_cast(float, u);
}

__device__ __forceinline__ unsigned pk2bf(float lo, float hi) {
    unsigned u;
    asm("v_cvt_pk_bf16_f32 %0, %1, %2" : "=v"(u) : "v"(lo), "v"(hi));
    return u;
}

__global__ void prep_scalars(const float* __restrict__ g1, const float* __restrict__ b1,
                             const float* __restrict__ m1, const float* __restrict__ v1,
                             const float* __restrict__ g2, const float* __restrict__ b2,
                             const float* __restrict__ m2, const float* __restrict__ v2,
                             float* __restrict__ wsf) {
    int t = threadIdx.x;  // h (0..255)
    float s1 = g1[t] * __frsqrt_rn(v1[t] + EPSV);
    float t1 = b1[t] - m1[t] * s1;
    float s2 = g2[t] * __frsqrt_rn(v2[t] + EPSV);
    float t2 = b2[t] - m2[t] * s2;
    wsf[OFF_S1 + t] = s1;
    wsf[OFF_T1 + t] = t1;
    wsf[OFF_T2 + t] = t2 * TWO_LOG2E;
}

// W1a fragments [16][64][8]: frag f = w*2+n, lane l: col=(f>>1)*32+(f&1)*16+(l&15),
// k = (l>>4)*8+e (k<16 real, else 0), val = W1[(256+k)*256+col]*s1[col]
__global__ void prep_w1f(const float* __restrict__ W1, float* __restrict__ wsf) {
    int tid = blockIdx.x * 256 + threadIdx.x;  // 0..1023
    int f = tid >> 6, l = tid & 63;
    int col = (f >> 1) * 32 + (f & 1) * 16 + (l & 15);
    int kb = (l >> 4) * 8;
    float s1 = wsf[OFF_S1 + col];
    short8 v;
#pragma unroll
    for (int e = 0; e < 8; ++e) {
        int k = kb + e;
        v[e] = (k < 16) ? f2bf(W1[(256 + k) * 256 + col] * s1) : (short)0;
    }
    *(short8*)((short*)(wsf + OFF_W1F) + tid * 8) = v;
}

// W2 fragments [128][64][8]: frag f = w*16+n*8+s, lane l: col = w*32+n*16+(l&15),
// k = s*32+(l>>4)*8+e, val = W2[k*256+col]*s2[col]*2log2e
__global__ void prep_w2f(const float* __restrict__ W2,
                         const float* __restrict__ g2, const float* __restrict__ v2,
                         float* __restrict__ wsf) {
    int tid = blockIdx.x * 256 + threadIdx.x;  // 0..8191
    int f = tid >> 6, l = tid & 63;
    int w = f >> 4, n = (f >> 3) & 1, s = f & 7;
    int col = w * 32 + n * 16 + (l & 15);
    int kb = s * 32 + (l >> 4) * 8;
    float s2 = g2[col] * __frsqrt_rn(v2[col] + EPSV) * TWO_LOG2E;
    short8 v;
#pragma unroll
    for (int e = 0; e < 8; ++e)
        v[e] = f2bf(W2[(kb + e) * 256 + col] * s2);
    *(short8*)((short*)(wsf + OFF_W2F) + tid * 8) = v;
}

// P1t f32 + P2T bf16 transposed image [b][h][j]
__global__ void prep_p(const float* __restrict__ inp, const float* __restrict__ W1,
                       float* __restrict__ wsf) {
    int bn = blockIdx.x, h = threadIdx.x;
    const float* x = inp + (size_t)bn * 128;
    float a1 = 0.f, a2 = 0.f;
    for (int c = 0; c < 128; ++c) {
        float xv = x[c];
        a1 = fmaf(xv, W1[c * 256 + h], a1);
        a2 = fmaf(xv, W1[(128 + c) * 256 + h], a2);
    }
    float s1 = wsf[OFF_S1 + h], t1 = wsf[OFF_T1 + h];
    wsf[OFF_P1T + (size_t)bn * 256 + h] = a1 * s1 + t1;
    int b = bn >> 9, j = bn & 511;
    short* img = (short*)(wsf + OFF_P2T);
    img[((size_t)b * 256 + h) * 512 + j] = f2bf(a2 * s1);
}

__global__ __launch_bounds__(512, 4) void propmain(
    const float* __restrict__ adj, const float* __restrict__ wsf,
    float* __restrict__ out) {
    __shared__ __align__(16) short h1b[32 * 256];   // bf16 H1, &15-swizzled (16 KB)
    __shared__ __align__(16) short adjbf[32 * 32];  // bf16 adj tile, chunk-XOR (2 KB)

    const int bi = blockIdx.x;
    const int b = bi >> 9;
    const int t = threadIdx.x;
    const int w = t >> 6, l = t & 63, r = l & 15, q = l >> 4;

    const float* P1t = wsf + OFF_P1T;
    const float* t2p = wsf + OFF_T2;
    const short* W1f = (const short*)(wsf + OFF_W1F);
    const short* W2f = (const short*)(wsf + OFF_W2F);
    const short* p2T = (const short*)(wsf + OFF_P2T) + ((size_t)b << 17);  // [h][512 j]
    const float* adjbase = adj + (size_t)bi * 512 * 16;

    float t2v[2], p1v[2];
#pragma unroll
    for (int n = 0; n < 2; ++n) {
        const int hc = w * 32 + n * 16 + r;
        t2v[n] = t2p[hc];
        p1v[n] = P1t[(size_t)bi * 256 + hc];
    }

    // adj staging constants (32-row tile; t<256 threads participate)
    const int arow_st = (t & 255) >> 3, ks_st = (t & 7) * 2;
    const int aslot = arow_st * 32 + (((ks_st >> 3) ^ (arow_st & 3)) << 3) + (ks_st & 7);

    // P2 prefetch bases: frag (rf,n) -> p2T[(w*32+n*16+r)][jt*32 + rf*16 + q*4 .. +3]
    const short* p2l[2];
#pragma unroll
    for (int n = 0; n < 2; ++n)
        p2l[n] = p2T + (size_t)(w * 32 + n * 16 + r) * 512 + q * 4;  // + jt*32 + rf*16

    unsigned stadj;
#define LOAD_ADJ(JT) do {                                                       \
        if (t < 256) {                                                          \
            const float2 _av = *(const float2*)(adjbase + (JT) * 512 + t * 2);  \
            stadj = pk2bf(_av.x, _av.y);                                        \
        }                                                                       \
    } while (0)

    // prologue: zero adjbf pads, stage adj tile 0
    if (t < 128) {
        short8 z = {0, 0, 0, 0, 0, 0, 0, 0};
        *(short8*)(adjbf + t * 8) = z;
    }
    LOAD_ADJ(0);
    __syncthreads();   // zeros visible before adj data writes
    if (t < 256) *(unsigned*)(adjbf + aslot) = stadj;

    float part[2] = {0.f, 0.f};

    for (int jt = 0; jt < 16; ++jt) {
        __syncthreads();  // (A) adjbf(jt) visible; h1b free for rewrite

        // P2 register prefetch for this tile (4 x b64 from L2), issued early
        sh4 p2f[2][2];
#pragma unroll
        for (int rf = 0; rf < 2; ++rf)
#pragma unroll
            for (int n = 0; n < 2; ++n)
                p2f[rf][n] = *(const sh4*)(p2l[n] + jt * 32 + rf * 16);

        if (jt < 15) LOAD_ADJ(jt + 1);  // global->reg, hides under phase 1

        // ---- phase 1: acc = P1 + adj@W1a (MFMA); epilogue += P2, relu -> h1b ----
        const short* w1fw = W1f + (w * 2) * 512 + l * 8;
        const short8 bB1_0 = *(const short8*)(w1fw);
        const short8 bB1_1 = *(const short8*)(w1fw + 512);
#pragma unroll
        for (int rf = 0; rf < 2; ++rf) {
            const int arow = rf * 16 + r;
            const short8 aA1 = *(const short8*)(adjbf + arow * 32 + (q ^ (r & 3)) * 8);
            f32x4 a0 = {p1v[0], p1v[0], p1v[0], p1v[0]};
            f32x4 a1 = {p1v[1], p1v[1], p1v[1], p1v[1]};
            a0 = __builtin_amdgcn_mfma_f32_16x16x32_bf16(aA1, bB1_0, a0, 0, 0, 0);
            a1 = __builtin_amdgcn_mfma_f32_16x16x32_bf16(aA1, bB1_1, a1, 0, 0, 0);
#pragma unroll
            for (int n = 0; n < 2; ++n) {
                const f32x4 av = n ? a1 : a0;
                const int colb = w * 32 + n * 16 + r;
#pragma unroll
                for (int e = 0; e < 4; ++e) {
                    const int row2 = rf * 16 + q * 4 + e;
                    const float y = fmaxf(av[e] + bf2f(p2f[rf][n][e]), 0.f);
                    h1b[(row2 << 8) + (colb ^ ((row2 & 15) << 3))] = f2bf(y);
                }
            }
        }
        __syncthreads();  // (B) h1b visible; adjbf reads of tile jt done

        if (jt < 15 && t < 256) *(unsigned*)(adjbf + aslot) = stadj;  // adj jt+1

        // ---- phase 2: h1b @ W2 (frags loaded per s-step, blinded base) ----
        {
            const short* W2p = W2f + w * 8192 + l * 8;
            asm volatile("" : "+v"(W2p));  // opaque per tile: no hoist across jt
            f32x4 acc[2][2];
#pragma unroll
            for (int rf = 0; rf < 2; ++rf)
#pragma unroll
                for (int n = 0; n < 2; ++n)
                    acc[rf][n] = (f32x4){t2v[n], t2v[n], t2v[n], t2v[n]};
#pragma unroll
            for (int s = 0; s < 8; ++s) {
                const short8 f0 = *(const short8*)(W2p + s * 512);
                const short8 f1 = *(const short8*)(W2p + (8 + s) * 512);
#pragma unroll
                for (int rf = 0; rf < 2; ++rf) {
                    const int row = rf * 16 + r;
                    const short8 aA = *(const short8*)(
                        h1b + (row << 8) + ((s * 32 + q * 8) ^ ((row & 15) << 3)));
                    acc[rf][0] = __builtin_amdgcn_mfma_f32_16x16x32_bf16(
                        aA, f0, acc[rf][0], 0, 0, 0);
                    acc[rf][1] = __builtin_amdgcn_mfma_f32_16x16x32_bf16(
                        aA, f1, acc[rf][1], 0, 0, 0);
                }
            }
#pragma unroll
            for (int n = 0; n < 2; ++n) {
                float ps = 0.f;
#pragma unroll
                for (int rf = 0; rf < 2; ++rf)
#pragma unroll
                    for (int e = 0; e < 4; ++e) {
                        const float ex = exp2f(acc[rf][n][e]);
                        ps += __builtin_amdgcn_rcpf(ex + 1.f);
                    }
                part[n] += ps;
            }
        }
    }

    // sum_j tanh = 512 - 2*sum(rcp); reduce over q
#pragma unroll
    for (int n = 0; n < 2; ++n) {
        float v = part[n];
        v += __shfl_xor(v, 16, 64);
        v += __shfl_xor(v, 32, 64);
        if (q == 0) out[(size_t)bi * 256 + w * 32 + n * 16 + r] = 512.f - 2.f * v;
    }
#undef LOAD_ADJ
}

extern "C" void kernel_launch(void* const* d_in, const int* in_sizes, int n_in,
                              void* d_out, int out_size, void* d_ws, size_t ws_size,
                              hipStream_t stream) {
    (void)in_sizes; (void)n_in; (void)out_size; (void)ws_size;
    const float* inputs = (const float*)d_in[0];
    const float* adj    = (const float*)d_in[1];
    const float* W1     = (const float*)d_in[2];
    const float* g1     = (const float*)d_in[3];
    const float* b1     = (const float*)d_in[4];
    const float* m1     = (const float*)d_in[5];
    const float* v1     = (const float*)d_in[6];
    const float* W2     = (const float*)d_in[7];
    const float* g2     = (const float*)d_in[8];
    const float* b2     = (const float*)d_in[9];
    const float* m2     = (const float*)d_in[10];
    const float* v2     = (const float*)d_in[11];
    float* out = (float*)d_out;
    float* wsf = (float*)d_ws;

    prep_scalars<<<1, 256, 0, stream>>>(g1, b1, m1, v1, g2, b2, m2, v2, wsf);
    prep_w1f<<<4, 256, 0, stream>>>(W1, wsf);
    prep_w2f<<<32, 256, 0, stream>>>(W2, g2, v2, wsf);
    prep_p<<<1024, 256, 0, stream>>>(inputs, W1, wsf);
    propmain<<<1024, 512, 0, stream>>>(adj, wsf, out);
}

// Round 12
// 147.265 us; speedup vs baseline: 1.2260x; 1.2233x over previous
//
#include <hip/hip_runtime.h>
#include <hip/hip_bf16.h>

// out[b,i,k] = sum_j tanh(bn2( relu(bn1( [x_i,x_j,adj_ij] @ W1 )) @ W2 ))[k]
// Phase-1 (swapped): D[h][j] = mfma(A=W1a^T, B=adj) + P1[h]; epilogue += P2[j][h]
//   (f32x4 global prefetch), relu -> packed b64 writes into h1b.
// Phase-2: h1b @ W2 frags loaded per s-step from L2 (blinded ptr).
// LDS 36 KB (h1b 32K + adj 4K). No scalar LDS ops anywhere.

typedef short short8 __attribute__((ext_vector_type(8)));
typedef float f32x4 __attribute__((ext_vector_type(4)));
typedef unsigned int u32x2 __attribute__((ext_vector_type(2)));

#define EPSV 1e-5f
#define TWO_LOG2E 2.885390081777927f

// ws float offsets
#define OFF_P1T  0         // [1024][256] f32
#define OFF_P2S  262144    // [1024][256] f32 row-major ([b*512+j][h])
#define OFF_S1   524288
#define OFF_T1   524544
#define OFF_T2   524800    // t2 * 2log2e
#define OFF_W1F  525056    // bf16 frags [16][64][8] = 4096 floats
#define OFF_W2F  529152    // bf16 frags [128][64][8] = 32768 floats

__device__ __forceinline__ short f2bf(float f) {
    unsigned u = __builtin_bit_cast(unsigned, f);
    u += 0x7fffu + ((u >> 16) & 1u);
    return (short)(u >> 16);
}

__device__ __forceinline__ unsigned pk2bf(float lo, float hi) {
    unsigned u;
    asm("v_cvt_pk_bf16_f32 %0, %1, %2" : "=v"(u) : "v"(lo), "v"(hi));
    return u;
}

__global__ void prep_scalars(const float* __restrict__ g1, const float* __restrict__ b1,
                             const float* __restrict__ m1, const float* __restrict__ v1,
                             const float* __restrict__ g2, const float* __restrict__ b2,
                             const float* __restrict__ m2, const float* __restrict__ v2,
                             float* __restrict__ wsf) {
    int t = threadIdx.x;  // h (0..255)
    float s1 = g1[t] * __frsqrt_rn(v1[t] + EPSV);
    float t1 = b1[t] - m1[t] * s1;
    float s2 = g2[t] * __frsqrt_rn(v2[t] + EPSV);
    float t2 = b2[t] - m2[t] * s2;
    wsf[OFF_S1 + t] = s1;
    wsf[OFF_T1 + t] = t1;
    wsf[OFF_T2 + t] = t2 * TWO_LOG2E;
}

// W1a fragments [16][64][8]: frag f, lane l: h-col=(f>>1)*32+(f&1)*16+(l&15),
// k=(l>>4)*8+e (k<16 real, else 0), val = W1[(256+k)*256+h]*s1[h]
// (identical lane-mapping serves as A-frag of W1a^T in the swapped MFMA)
__global__ void prep_w1f(const float* __restrict__ W1, float* __restrict__ wsf) {
    int tid = blockIdx.x * 256 + threadIdx.x;  // 0..1023
    int f = tid >> 6, l = tid & 63;
    int col = (f >> 1) * 32 + (f & 1) * 16 + (l & 15);
    int kb = (l >> 4) * 8;
    float s1 = wsf[OFF_S1 + col];
    short8 v;
#pragma unroll
    for (int e = 0; e < 8; ++e) {
        int k = kb + e;
        v[e] = (k < 16) ? f2bf(W1[(256 + k) * 256 + col] * s1) : (short)0;
    }
    *(short8*)((short*)(wsf + OFF_W1F) + tid * 8) = v;
}

// W2 fragments [128][64][8]: frag f = w*16+n*8+s, lane l: col = w*32+n*16+(l&15),
// k = s*32+(l>>4)*8+e, val = W2[k*256+col]*s2[col]*2log2e
__global__ void prep_w2f(const float* __restrict__ W2,
                         const float* __restrict__ g2, const float* __restrict__ v2,
                         float* __restrict__ wsf) {
    int tid = blockIdx.x * 256 + threadIdx.x;  // 0..8191
    int f = tid >> 6, l = tid & 63;
    int w = f >> 4, n = (f >> 3) & 1, s = f & 7;
    int col = w * 32 + n * 16 + (l & 15);
    int kb = s * 32 + (l >> 4) * 8;
    float s2 = g2[col] * __frsqrt_rn(v2[col] + EPSV) * TWO_LOG2E;
    short8 v;
#pragma unroll
    for (int e = 0; e < 8; ++e)
        v[e] = f2bf(W2[(kb + e) * 256 + col] * s2);
    *(short8*)((short*)(wsf + OFF_W2F) + tid * 8) = v;
}

// P1t f32 + P2S f32 row-major
__global__ void prep_p(const float* __restrict__ inp, const float* __restrict__ W1,
                       float* __restrict__ wsf) {
    int bn = blockIdx.x, h = threadIdx.x;
    const float* x = inp + (size_t)bn * 128;
    float a1 = 0.f, a2 = 0.f;
    for (int c = 0; c < 128; ++c) {
        float xv = x[c];
        a1 = fmaf(xv, W1[c * 256 + h], a1);
        a2 = fmaf(xv, W1[(128 + c) * 256 + h], a2);
    }
    float s1 = wsf[OFF_S1 + h], t1 = wsf[OFF_T1 + h];
    wsf[OFF_P1T + (size_t)bn * 256 + h] = a1 * s1 + t1;
    wsf[OFF_P2S + (size_t)bn * 256 + h] = a2 * s1;
}

__global__ __launch_bounds__(512, 4) void propmain(
    const float* __restrict__ adj, const float* __restrict__ wsf,
    float* __restrict__ out) {
    __shared__ __align__(16) short h1b[64 * 256];   // bf16 H1, (r&7)-XOR swizzled (32 KB)
    __shared__ __align__(16) short adjbf[64 * 32];  // bf16 adj tile, chunk-XOR (4 KB)

    const int bi = blockIdx.x;
    const int b = bi >> 9;
    const int t = threadIdx.x;
    const int w = t >> 6, l = t & 63, r = l & 15, q = l >> 4;

    const float* P1t = wsf + OFF_P1T;
    const float* P2s = wsf + OFF_P2S + (size_t)b * 512 * 256;
    const float* t2p = wsf + OFF_T2;
    const short* W1f = (const short*)(wsf + OFF_W1F);
    const short* W2f = (const short*)(wsf + OFF_W2F);
    const float* adjbase = adj + (size_t)bi * 512 * 16;

    // persistent A-frags (W1a^T) and per-lane biases
    const short* w1fw = W1f + (w * 2) * 512 + l * 8;
    const short8 aW1_0 = *(const short8*)(w1fw);
    const short8 aW1_1 = *(const short8*)(w1fw + 512);
    f32x4 p1v[2];
    float t2v[2];
#pragma unroll
    for (int na = 0; na < 2; ++na) {
        p1v[na] = *(const f32x4*)(P1t + (size_t)bi * 256 + w * 32 + na * 16 + q * 4);
        t2v[na] = t2p[w * 32 + na * 16 + r];
    }

    // adj staging constants (64-row tile, all 512 threads)
    const int arow_st = t >> 3, ks_st = (t & 7) * 2;
    const int aslot = arow_st * 32 + (((ks_st >> 3) ^ (arow_st & 3)) << 3) + (ks_st & 7);

    // per-lane P2 base: row j = r (+tile offsets), cols w*32+q*4 (+na*16)
    const float* p2base = P2s + (size_t)r * 256 + w * 32 + q * 4;

    unsigned stadj;
#define LOAD_ADJ(JT) do {                                                       \
        const float2 _av = *(const float2*)(adjbase + (JT) * 1024 + t * 2);     \
        stadj = pk2bf(_av.x, _av.y);                                            \
    } while (0)

    // prologue: zero adjbf (pads persist), stage adj tile 0
    if (t < 256) {
        short8 z = {0, 0, 0, 0, 0, 0, 0, 0};
        *(short8*)(adjbf + t * 8) = z;
    }
    LOAD_ADJ(0);
    __syncthreads();   // zeros visible before adj data writes
    *(unsigned*)(adjbf + aslot) = stadj;

    float part[2] = {0.f, 0.f};

    for (int jt = 0; jt < 8; ++jt) {
        __syncthreads();  // (A) adjbf(jt) visible; h1b free for rewrite

        // P2 prefetch for this tile: 8 x f32x4 (L2), issued before MFMAs
        f32x4 p2f[2][4];
#pragma unroll
        for (int na = 0; na < 2; ++na)
#pragma unroll
            for (int jb = 0; jb < 4; ++jb)
                p2f[na][jb] = *(const f32x4*)(p2base + (size_t)(jt * 64 + jb * 16) * 256 +
                                              na * 16);

        if (jt < 7) LOAD_ADJ(jt + 1);  // global->reg, hides under phase 1

        // ---- phase 1 (swapped): D[h][j] = W1a^T @ adj + P1 ----
        f32x4 acc1[2][4];
#pragma unroll
        for (int na = 0; na < 2; ++na)
#pragma unroll
            for (int jb = 0; jb < 4; ++jb) acc1[na][jb] = p1v[na];
#pragma unroll
        for (int jb = 0; jb < 4; ++jb) {
            const short8 bAdj = *(const short8*)(
                adjbf + (jb * 16 + r) * 32 + ((q ^ (r & 3)) << 3));
            acc1[0][jb] = __builtin_amdgcn_mfma_f32_16x16x32_bf16(
                aW1_0, bAdj, acc1[0][jb], 0, 0, 0);
            acc1[1][jb] = __builtin_amdgcn_mfma_f32_16x16x32_bf16(
                aW1_1, bAdj, acc1[1][jb], 0, 0, 0);
        }
        // epilogue: += P2, relu, pack 4 h -> one b64 write per frag
#pragma unroll
        for (int na = 0; na < 2; ++na)
#pragma unroll
            for (int jb = 0; jb < 4; ++jb) {
                const int j = jb * 16 + r;
                float y0 = fmaxf(acc1[na][jb][0] + p2f[na][jb][0], 0.f);
                float y1 = fmaxf(acc1[na][jb][1] + p2f[na][jb][1], 0.f);
                float y2 = fmaxf(acc1[na][jb][2] + p2f[na][jb][2], 0.f);
                float y3 = fmaxf(acc1[na][jb][3] + p2f[na][jb][3], 0.f);
                u32x2 pk;
                pk.x = pk2bf(y0, y1);
                pk.y = pk2bf(y2, y3);
                const int colb = (w * 32 + na * 16 + q * 4) ^ ((r & 7) << 3);
                *(u32x2*)(h1b + j * 256 + colb) = pk;
            }
        __syncthreads();  // (B) h1b visible; adjbf reads of tile jt done

        if (jt < 7) *(unsigned*)(adjbf + aslot) = stadj;  // adj tile jt+1

        // ---- phase 2: h1b @ W2 (frags loaded per s-step, blinded base) ----
        {
            const short* W2p = W2f + w * 8192 + l * 8;
            asm volatile("" : "+v"(W2p));  // opaque per tile: no hoist across jt
            f32x4 acc[4][2];
#pragma unroll
            for (int rf = 0; rf < 4; ++rf)
#pragma unroll
                for (int n = 0; n < 2; ++n)
                    acc[rf][n] = (f32x4){t2v[n], t2v[n], t2v[n], t2v[n]};
#pragma unroll
            for (int s = 0; s < 8; ++s) {
                const short8 f0 = *(const short8*)(W2p + s * 512);
                const short8 f1 = *(const short8*)(W2p + (8 + s) * 512);
#pragma unroll
                for (int rf = 0; rf < 4; ++rf) {
                    const int row = rf * 16 + r;
                    const short8 aA = *(const short8*)(
                        h1b + (row << 8) + ((s * 32 + q * 8) ^ ((r & 7) << 3)));
                    acc[rf][0] = __builtin_amdgcn_mfma_f32_16x16x32_bf16(
                        aA, f0, acc[rf][0], 0, 0, 0);
                    acc[rf][1] = __builtin_amdgcn_mfma_f32_16x16x32_bf16(
                        aA, f1, acc[rf][1], 0, 0, 0);
                }
            }
#pragma unroll
            for (int n = 0; n < 2; ++n) {
                float ps = 0.f;
#pragma unroll
                for (int rf = 0; rf < 4; ++rf)
#pragma unroll
                    for (int e = 0; e < 4; ++e) {
                        const float ex = exp2f(acc[rf][n][e]);
                        ps += __builtin_amdgcn_rcpf(ex + 1.f);
                    }
                part[n] += ps;
            }
        }
    }

    // sum_j tanh = 512 - 2*sum(rcp); reduce over q
#pragma unroll
    for (int n = 0; n < 2; ++n) {
        float v = part[n];
        v += __shfl_xor(v, 16, 64);
        v += __shfl_xor(v, 32, 64);
        if (q == 0) out[(size_t)bi * 256 + w * 32 + n * 16 + r] = 512.f - 2.f * v;
    }
#undef LOAD_ADJ
}

extern "C" void kernel_launch(void* const* d_in, const int* in_sizes, int n_in,
                              void* d_out, int out_size, void* d_ws, size_t ws_size,
                              hipStream_t stream) {
    (void)in_sizes; (void)n_in; (void)out_size; (void)ws_size;
    const float* inputs = (const float*)d_in[0];
    const float* adj    = (const float*)d_in[1];
    const float* W1     = (const float*)d_in[2];
    const float* g1     = (const float*)d_in[3];
    const float* b1     = (const float*)d_in[4];
    const float* m1     = (const float*)d_in[5];
    const float* v1     = (const float*)d_in[6];
    const float* W2     = (const float*)d_in[7];
    const float* g2     = (const float*)d_in[8];
    const float* b2     = (const float*)d_in[9];
    const float* m2     = (const float*)d_in[10];
    const float* v2     = (const float*)d_in[11];
    float* out = (float*)d_out;
    float* wsf = (float*)d_ws;

    prep_scalars<<<1, 256, 0, stream>>>(g1, b1, m1, v1, g2, b2, m2, v2, wsf);
    prep_w1f<<<4, 256, 0, stream>>>(W1, wsf);
    prep_w2f<<<32, 256, 0, stream>>>(W2, g2, v2, wsf);
    prep_p<<<1024, 256, 0, stream>>>(inputs, W1, wsf);
    propmain<<<1024, 512, 0, stream>>>(adj, wsf, out);
}